// Round 6
// baseline (179.186 us; speedup 1.0000x reference)
//
#include <hip/hip_runtime.h>

#define BB 8
#define CC 128
#define NN 4096   // H*W = 64*64

typedef __bf16 bf16x8_t __attribute__((ext_vector_type(8)));
typedef unsigned short u16x8 __attribute__((ext_vector_type(8)));
typedef float f32x4 __attribute__((ext_vector_type(4)));
typedef float f32x16 __attribute__((ext_vector_type(16)));
typedef unsigned int u32x4 __attribute__((ext_vector_type(4)));
typedef __attribute__((address_space(1))) const unsigned int gu32;
typedef __attribute__((address_space(3))) unsigned int lu32;

#define KSCALE 0.12753262456033348f   // (1/sqrt(128)) * log2(e)

__device__ __forceinline__ unsigned short f2bf(float f) {
  unsigned int u = __builtin_bit_cast(unsigned int, f);
  u += 0x7fffu + ((u >> 16) & 1u);          // RNE
  return (unsigned short)(u >> 16);
}

__device__ __forceinline__ float bf2f(unsigned short s) {
  unsigned int u = ((unsigned int)s) << 16;
  return __builtin_bit_cast(float, u);
}

__device__ __forceinline__ unsigned int cvt_pk_bf16(float lo, float hi) {
  unsigned int r;
  asm("v_cvt_pk_bf16_f32 %0, %1, %2" : "=v"(r) : "v"(lo), "v"(hi));
  return r;
}

__device__ __forceinline__ f32x4 mfma16(u16x8 a, u16x8 b, f32x4 c) {
  return __builtin_amdgcn_mfma_f32_16x16x32_bf16(
      __builtin_bit_cast(bf16x8_t, a), __builtin_bit_cast(bf16x8_t, b), c, 0, 0, 0);
}

__device__ __forceinline__ f32x16 mfma32(u16x8 a, u16x8 b, f32x16 c) {
  return __builtin_amdgcn_mfma_f32_32x32x16_bf16(
      __builtin_bit_cast(bf16x8_t, a), __builtin_bit_cast(bf16x8_t, b), c, 0, 0, 0);
}

// ---------------------------------------------------------------------------
// Kernel 0: prep.  Blocks 0..63: Wq*KSCALE, Wv -> bf16.  Block 64: csk[c]=sum_o Wk[o][c]
// ---------------------------------------------------------------------------
__global__ void prep(const float* __restrict__ Wq, const float* __restrict__ Wv,
                     const float* __restrict__ Wk,
                     unsigned short* __restrict__ Qwb, unsigned short* __restrict__ Vwb,
                     float* __restrict__ csk) {
  if (blockIdx.x < 64) {
    const int i = blockIdx.x * 256 + threadIdx.x;
    Qwb[i] = f2bf(Wq[i] * KSCALE);
    Vwb[i] = f2bf(Wv[i]);
  } else if (threadIdx.x < CC) {
    const int c = threadIdx.x;
    float s = 0.f;
    for (int o = 0; o < CC; ++o) s += Wk[(size_t)o * CC + c];
    csk[c] = s;
  }
}

// ---------------------------------------------------------------------------
// Kernel 1: QKV projection (as round 5, proven).
//  Q[b][n][o] = (x.Wq^T + bq) * KSCALE   bf16 pixel-major
//  K[b][n][c] =  x[c][n]*csk[c] + bk[c]  bf16 pixel-major
//  V[b][o][n] =  x.Wv^T + bv             bf16 channel-major
// ---------------------------------------------------------------------------
__global__ __launch_bounds__(256, 2) void qkv_proj(
    const float* __restrict__ x,
    const unsigned short* __restrict__ Qwb, const float* __restrict__ bq,
    const float* __restrict__ csk, const float* __restrict__ bk,
    const unsigned short* __restrict__ Vwb, const float* __restrict__ bv,
    unsigned short* __restrict__ Q,
    unsigned short* __restrict__ K,
    unsigned short* __restrict__ V)
{
  const int b  = blockIdx.x & 7;
  const int n0 = (blockIdx.x >> 3) << 6;
  const int t  = threadIdx.x;
  const int lane = t & 63;
  const int w  = t >> 6;
  const int lq = lane & 15;
  const int g  = lane >> 4;

  __shared__ unsigned short xs[64][136];
  __shared__ unsigned short ks[64][136];
  __shared__ unsigned short vs[128][72];

  {
    const int n = t & 63;
    const float* xp = x + (size_t)b * (CC * NN) + n0 + n;
    for (int c = t >> 6; c < CC; c += 4) {
      const float xv = xp[(size_t)c * NN];
      xs[n][c] = f2bf(xv);
      ks[n][c] = f2bf(xv * csk[c] + bk[c]);
    }
  }
  __syncthreads();

  u16x8 a[4];
  {
    const unsigned short* ap = &xs[w * 16 + lq][g * 8];
    for (int ksl = 0; ksl < 4; ++ksl) a[ksl] = *(const u16x8*)(ap + ksl * 32);
  }

  for (int ot = 0; ot < 8; ++ot) {
    f32x4 aq = {0.f,0.f,0.f,0.f}, av = {0.f,0.f,0.f,0.f};
    const int o = ot * 16 + lq;
    const unsigned short* wq = Qwb + (size_t)o * CC + g * 8;
    const unsigned short* wv = Vwb + (size_t)o * CC + g * 8;
    for (int ksl = 0; ksl < 4; ++ksl) {
      aq = mfma16(a[ksl], *(const u16x8*)(wq + ksl * 32), aq);
      av = mfma16(a[ksl], *(const u16x8*)(wv + ksl * 32), av);
    }
    const float bqv = bq[o] * KSCALE, bvv = bv[o];
    for (int r = 0; r < 4; ++r) {
      const int nl = w * 16 + g * 4 + r;
      Q[((size_t)b * NN + n0 + nl) * CC + o] = f2bf(aq[r] + bqv);
      vs[o][nl] = f2bf(av[r] + bvv);
    }
  }
  __syncthreads();

  {
    unsigned short* kout = K + ((size_t)b * NN + n0) * CC;
    for (int i = t; i < 64 * 16; i += 256) {
      const int n = i >> 4, oc = (i & 15) * 8;
      *(uint4*)(kout + (size_t)n * CC + oc) = *(const uint4*)&ks[n][oc];
    }
  }
  {
    unsigned short* vout = V + (size_t)b * (CC * NN) + n0;
    for (int i = t; i < 128 * 32; i += 256) {
      const int c  = i >> 5;
      const int np = (i & 31) << 1;
      *(unsigned int*)(vout + (size_t)c * NN + np) = *(const unsigned int*)&vs[c][np];
    }
  }
}

// ---------------------------------------------------------------------------
// Kernel 2: flash attention partials, 32x32x16 MFMA, KV split 4-way.
// Block: 256 thr = 4 waves x 32 q-rows; KV tiles of 32 keys, double-buffered.
// S^T = mfma32(K, Q): lane holds 16 scores of q = lane&31 (keys split by lane-half).
// P re-fragmented IN REGISTERS via cvt_pk + v_permlane32_swap (no LDS round-trip).
// O^T = mfma32(V^T, P^T): rows = channel -> channel-major partial store.
// LDS 32KB/block -> 4 blocks/CU; all LDS reads conflict-free by construction.
// ---------------------------------------------------------------------------
__global__ __launch_bounds__(256, 4) void flash_attn(
    const unsigned short* __restrict__ Q,
    const unsigned short* __restrict__ K,
    const unsigned short* __restrict__ V,
    float* __restrict__ PO0,             // split 0: fp32 normalized partial (d_out)
    unsigned short* __restrict__ PO123,  // splits 1..3: bf16 normalized partials
    float2* __restrict__ PML)
{
  const int bid = blockIdx.x;
  const int b   = bid & 7;               // batch -> XCD-local KV
  const int qb  = (bid >> 3) & 31;
  const int sp  = bid >> 8;              // KV quarter 0..3
  const int kv0 = sp << 10;
  const int t   = threadIdx.x;
  const int lane = t & 63;
  const int w   = t >> 6;                // wave 0..3, 32 q-rows each
  const int cl  = lane & 31;
  const int hi  = lane >> 5;
  const int q0w = (qb << 7) + (w << 5);

  __shared__ unsigned short KtL[2][32 * 128];   // 8KB: [key][c], (row&7)<<4 swizzle
  __shared__ unsigned short VlL[2][64 * 64];    // 8KB: row-pairs [c>>1][128B], swizzled

  // Q B-frags: col q = cl, k-slice = ks*16 + hi*8
  u16x8 qf[8];
  {
    const unsigned short* qp = Q + ((size_t)b * NN + q0w + cl) * CC + hi * 8;
    #pragma unroll
    for (int ks = 0; ks < 8; ++ks) qf[ks] = *(const u16x8*)(qp + ks * 16);
  }

  // ---- staging offsets (pre-swizzled global source, linear LDS dest) ----
  const char* kgb = (const char*)(K + (size_t)b * NN * CC);   // 256B rows
  const char* vgb = (const char*)(V + (size_t)b * CC * NN);   // 8192B rows
  int soK[2], soV[2], voC[2];
  #pragma unroll
  for (int j = 0; j < 2; ++j) {
    const int a = t * 16 + j * 4096;
    const int krow = a >> 8;
    soK[j] = (a & ~255) | ((a & 255) ^ ((krow & 7) << 4));
    const int rp = a >> 7;
    const int L = (a & 127) ^ ((rp & 7) << 4);
    const int c = rp * 2 + (L >> 6);
    voC[j] = c * (NN * 2);
    soV[j] = L & 63;                      // key*2 within tile
  }
  const int p0 = t * 16;

  #define STAGE(nb, kv) do {                                                      \
    const char* kg_ = kgb + ((size_t)(kv) << 8);                                  \
    const char* vg_ = vgb + ((size_t)(kv) << 1);                                  \
    __builtin_amdgcn_global_load_lds((gu32*)(kg_ + soK[0]),                       \
        (lu32*)((char*)&KtL[nb][0] + p0), 16, 0, 0);                              \
    __builtin_amdgcn_global_load_lds((gu32*)(kg_ + soK[1]),                       \
        (lu32*)((char*)&KtL[nb][0] + p0 + 4096), 16, 0, 0);                       \
    __builtin_amdgcn_global_load_lds((gu32*)(vg_ + voC[0] + soV[0]),              \
        (lu32*)((char*)&VlL[nb][0] + p0), 16, 0, 0);                              \
    __builtin_amdgcn_global_load_lds((gu32*)(vg_ + voC[1] + soV[1]),              \
        (lu32*)((char*)&VlL[nb][0] + p0 + 4096), 16, 0, 0);                       \
  } while (0)

  f32x16 oacc[4];
  #pragma unroll
  for (int i = 0; i < 4; ++i)
    #pragma unroll
    for (int r = 0; r < 16; ++r) oacc[i][r] = 0.f;
  float m_run = -1e30f, l_run = 0.f;

  const int swzK = (lane & 7) << 4;          // K read swizzle: row = cl, row&7 = lane&7
  const int swzV = ((cl >> 1) & 7) << 4;     // V read swizzle: rowpair&7

  STAGE(0, kv0);

  for (int tt = 0; tt < 32; ++tt) {
    const int cur = tt & 1;
    if (tt < 31) {
      STAGE(cur ^ 1, kv0 + (tt + 1) * 32);
      asm volatile("s_waitcnt vmcnt(4)" ::: "memory");
    } else {
      asm volatile("s_waitcnt vmcnt(0)" ::: "memory");
    }
    __builtin_amdgcn_s_barrier();

    // ---- S^T = K . Q^T : 8 chained mfma32 over C=128 ----
    const char* kb = (const char*)&KtL[cur][0] + cl * 256;
    f32x16 s;
    #pragma unroll
    for (int r = 0; r < 16; ++r) s[r] = 0.f;
    __builtin_amdgcn_s_setprio(1);
    #pragma unroll
    for (int ks = 0; ks < 8; ++ks) {
      u16x8 kf = *(const u16x8*)(kb + ((ks * 32 + hi * 16) ^ swzK));
      s = mfma32(kf, qf[ks], s);
    }
    __builtin_amdgcn_s_setprio(0);

    // ---- online softmax for q = cl (keys split across lane halves) ----
    float pm = s[0];
    #pragma unroll
    for (int r = 1; r < 16; ++r) pm = fmaxf(pm, s[r]);
    pm = fmaxf(pm, __shfl_xor(pm, 32));
    if (!__all(pm - m_run <= 8.0f)) {      // defer-max (T13)
      const float m_new = fmaxf(m_run, pm);
      const float alpha = exp2f(m_run - m_new);
      l_run *= alpha;
      #pragma unroll
      for (int i = 0; i < 4; ++i)
        #pragma unroll
        for (int r = 0; r < 16; ++r) oacc[i][r] *= alpha;
      m_run = m_new;
    }
    float e[16];
    #pragma unroll
    for (int r = 0; r < 16; ++r) e[r] = exp2f(s[r] - m_run);
    float l0 = (e[0] + e[1]) + (e[2] + e[3]);
    float l1 = (e[4] + e[5]) + (e[6] + e[7]);
    float l2 = (e[8] + e[9]) + (e[10] + e[11]);
    float l3 = (e[12] + e[13]) + (e[14] + e[15]);
    float lsum = (l0 + l1) + (l2 + l3);
    lsum += __shfl_xor(lsum, 32);
    l_run += lsum;

    // ---- P -> bf16 B-frags in-register (T12: cvt_pk + permlane32_swap) ----
    unsigned pk0 = cvt_pk_bf16(e[0], e[1]),   pk1 = cvt_pk_bf16(e[2], e[3]);
    unsigned pk2 = cvt_pk_bf16(e[4], e[5]),   pk3 = cvt_pk_bf16(e[6], e[7]);
    unsigned pk4 = cvt_pk_bf16(e[8], e[9]),   pk5 = cvt_pk_bf16(e[10], e[11]);
    unsigned pk6 = cvt_pk_bf16(e[12], e[13]), pk7 = cvt_pk_bf16(e[14], e[15]);
    asm("v_permlane32_swap_b32 %0, %1" : "+v"(pk0), "+v"(pk2));
    asm("v_permlane32_swap_b32 %0, %1" : "+v"(pk1), "+v"(pk3));
    asm("v_permlane32_swap_b32 %0, %1" : "+v"(pk4), "+v"(pk6));
    asm("v_permlane32_swap_b32 %0, %1" : "+v"(pk5), "+v"(pk7));
    u32x4 pw0 = {pk0, pk1, pk2, pk3};
    u32x4 pw1 = {pk4, pk5, pk6, pk7};
    const u16x8 pf0 = __builtin_bit_cast(u16x8, pw0);   // keys 0..15 slice
    const u16x8 pf1 = __builtin_bit_cast(u16x8, pw1);   // keys 16..31 slice

    // ---- O^T += V^T . P^T ----
    const char* vbb = (const char*)&VlL[cur][0] + (cl >> 1) * 128;
    const int o0 = (((cl & 1) << 6) | (hi << 4)) ^ swzV;
    __builtin_amdgcn_s_setprio(1);
    #pragma unroll
    for (int ct = 0; ct < 4; ++ct) {
      const char* vp = vbb + ct * 2048;           // 16 row-pairs per ct
      u16x8 vf0 = *(const u16x8*)(vp + o0);
      oacc[ct] = mfma32(vf0, pf0, oacc[ct]);
      u16x8 vf1 = *(const u16x8*)(vp + (o0 ^ 32));
      oacc[ct] = mfma32(vf1, pf1, oacc[ct]);
    }
    __builtin_amdgcn_s_setprio(0);
    asm volatile("s_waitcnt lgkmcnt(0)" ::: "memory");
    __builtin_amdgcn_s_barrier();
  }
  #undef STAGE

  // ---- epilogue: normalized partials, channel-major ----
  const float rinv = 1.0f / l_run;
  const int n = q0w + cl;
  if (sp == 0) {
    float* po = PO0 + (size_t)b * (CC * NN);
    #pragma unroll
    for (int ct = 0; ct < 4; ++ct)
      #pragma unroll
      for (int r = 0; r < 16; ++r) {
        const int c = ct * 32 + (r & 3) + 8 * (r >> 2) + 4 * hi;
        po[(size_t)c * NN + n] = oacc[ct][r] * rinv;
      }
  } else {
    unsigned short* po = PO123 + (size_t)(sp - 1) * (BB * CC * NN) + (size_t)b * (CC * NN);
    #pragma unroll
    for (int ct = 0; ct < 4; ++ct)
      #pragma unroll
      for (int r = 0; r < 16; ++r) {
        const int c = ct * 32 + (r & 3) + 8 * (r >> 2) + 4 * hi;
        po[(size_t)c * NN + n] = f2bf(oacc[ct][r] * rinv);
      }
  }
  if (hi == 0) PML[((size_t)sp * BB + b) * NN + n] = float2{m_run, l_run};
}

// ---------------------------------------------------------------------------
// Kernel 3: combine 4 KV-quarter partials + residual.
// out = x + sum_s wgt_s * o_s,  wgt_s = l_s*exp2(m_s-M) / sum(l*exp2(m-M))
// ---------------------------------------------------------------------------
__global__ __launch_bounds__(256) void combine(
    const float* __restrict__ x,
    const unsigned short* __restrict__ PO123,
    const float2* __restrict__ PML,
    float* __restrict__ out)                    // in: PO0 fp32, out: final
{
  const int bid = blockIdx.x;                   // 512 = 8 b x 64 n-chunks
  const int b = bid & 7;
  const int n = ((bid >> 3) << 6) + (threadIdx.x & 63);
  const int cq = threadIdx.x >> 6;
  float m[4], l[4];
  #pragma unroll
  for (int s = 0; s < 4; ++s) {
    const float2 ml = PML[((size_t)s * BB + b) * NN + n];
    m[s] = ml.x; l[s] = ml.y;
  }
  const float M = fmaxf(fmaxf(m[0], m[1]), fmaxf(m[2], m[3]));
  float wgt[4];
  #pragma unroll
  for (int s = 0; s < 4; ++s) wgt[s] = l[s] * exp2f(m[s] - M);
  const float inv = 1.0f / (((wgt[0] + wgt[1]) + (wgt[2] + wgt[3])));
  #pragma unroll
  for (int s = 0; s < 4; ++s) wgt[s] *= inv;

  const size_t base = (size_t)b * (CC * NN) + n;
  for (int c = cq; c < CC; c += 4) {
    const size_t idx = base + (size_t)c * NN;
    float acc = wgt[0] * out[idx];
    acc += wgt[1] * bf2f(PO123[idx]);
    acc += wgt[2] * bf2f(PO123[(size_t)(BB * CC * NN) + idx]);
    acc += wgt[3] * bf2f(PO123[(size_t)(2 * BB * CC * NN) + idx]);
    out[idx] = x[idx] + acc;
  }
}

extern "C" void kernel_launch(void* const* d_in, const int* in_sizes, int n_in,
                              void* d_out, int out_size, void* d_ws, size_t ws_size,
                              hipStream_t stream) {
  (void)in_sizes; (void)n_in; (void)out_size; (void)ws_size;
  const float* x  = (const float*)d_in[0];
  const float* Wq = (const float*)d_in[1];
  const float* bq = (const float*)d_in[2];
  const float* Wk = (const float*)d_in[3];
  const float* bk = (const float*)d_in[4];
  const float* Wv = (const float*)d_in[5];
  const float* bv = (const float*)d_in[6];

  unsigned short* Q     = (unsigned short*)d_ws;                  // 8 MB
  unsigned short* K     = Q + (size_t)BB * NN * CC;               // 8 MB
  unsigned short* V     = K + (size_t)BB * NN * CC;               // 8 MB
  unsigned short* PO123 = V + (size_t)BB * NN * CC;               // 24 MB (3 bf16 partials)
  float2* PML           = (float2*)(PO123 + (size_t)3 * BB * CC * NN); // 1 MB
  unsigned short* Qwb   = (unsigned short*)(PML + (size_t)4 * BB * NN); // 32 KB
  unsigned short* Vwb   = Qwb + (size_t)CC * CC;                  // 32 KB
  float* csk = (float*)(Vwb + (size_t)CC * CC);                   // 512 B
  float* out = (float*)d_out;                                     // also fp32 partial 0

  prep<<<dim3(65), dim3(256), 0, stream>>>(Wq, Wv, Wk, Qwb, Vwb, csk);
  qkv_proj<<<dim3(BB * (NN / 64)), dim3(256), 0, stream>>>(x, Qwb, bq, csk, bk, Vwb, bv, Q, K, V);
  flash_attn<<<dim3(BB * 32 * 4), dim3(256), 0, stream>>>(Q, K, V, out, PO123, PML);
  combine<<<dim3(BB * (NN / 64)), dim3(256), 0, stream>>>(x, PO123, PML, out);
}